// Round 2
// baseline (324.575 us; speedup 1.0000x reference)
//
#include <hip/hip_runtime.h>
#include <hip/hip_bf16.h>
#include <math.h>
#include <stdint.h>

// InfoNCE fused: sim = A @ B^T / T  (8192x8192x512, fp32 in)
// loss = mean_i( logsumexp_j sim[i,j] - sim[i,i] )
// bf16 MFMA GEMM fused with per-lane online logsumexp; diag in fp32.

#define NB 8192
#define DDIM 512
#define SPLITS 16
#define BM 128
#define BN 128
#define BK 32
#define CPB (NB / SPLITS)   // 512 cols per block
#define TPB (CPB / BN)      // 4 col tiles per block

typedef unsigned short u16;
typedef __attribute__((ext_vector_type(8))) short short8;
typedef __attribute__((ext_vector_type(4))) float f32x4;

__device__ __forceinline__ u16 f2bf(float f) {
  unsigned u = __float_as_uint(f);
  u += 0x7FFFu + ((u >> 16) & 1u);   // round-to-nearest-even
  return (u16)(u >> 16);
}

// global -> LDS direct copy, 16B per lane: HW writes ldsbase + lane*16.
__device__ __forceinline__ void gl2lds16(const u16* g, const u16* l) {
  __builtin_amdgcn_global_load_lds(
      (__attribute__((address_space(1))) unsigned int*)(uintptr_t)g,
      (__attribute__((address_space(3))) unsigned int*)(unsigned int)(uintptr_t)l,
      16, 0, 0);
}

// One wave per row: convert a & p rows to bf16 and compute diag dot in fp32.
__global__ void cvt_diag_kernel(const float* __restrict__ a, const float* __restrict__ p,
                                u16* __restrict__ ab, u16* __restrict__ pb,
                                float* __restrict__ diag) {
  int row = (blockIdx.x * 256 + threadIdx.x) >> 6;
  int lane = threadIdx.x & 63;
  const float4* ar = (const float4*)(a + (size_t)row * DDIM + lane * 8);
  const float4* pr = (const float4*)(p + (size_t)row * DDIM + lane * 8);
  float4 a0 = ar[0], a1 = ar[1];
  float4 p0 = pr[0], p1 = pr[1];
  ushort4* abr = (ushort4*)(ab + (size_t)row * DDIM + lane * 8);
  ushort4* pbr = (ushort4*)(pb + (size_t)row * DDIM + lane * 8);
  abr[0] = (ushort4){f2bf(a0.x), f2bf(a0.y), f2bf(a0.z), f2bf(a0.w)};
  abr[1] = (ushort4){f2bf(a1.x), f2bf(a1.y), f2bf(a1.z), f2bf(a1.w)};
  pbr[0] = (ushort4){f2bf(p0.x), f2bf(p0.y), f2bf(p0.z), f2bf(p0.w)};
  pbr[1] = (ushort4){f2bf(p1.x), f2bf(p1.y), f2bf(p1.z), f2bf(p1.w)};
  float s = a0.x * p0.x + a0.y * p0.y + a0.z * p0.z + a0.w * p0.w +
            a1.x * p1.x + a1.y * p1.y + a1.z * p1.z + a1.w * p1.w;
  for (int off = 32; off > 0; off >>= 1) s += __shfl_down(s, off);
  if (lane == 0) diag[row] = s * 10.0f;  // / T
}

__global__ __launch_bounds__(256, 4) void gemm_lse(
    const u16* __restrict__ Abf, const u16* __restrict__ Bbf,
    float* __restrict__ partM, float* __restrict__ partL) {
  // k-major chunk layout: 16B chunk (kc,row) at elem (kc*128 + row)*8.
  // Fragment ds_read_b128 is then lane-contiguous -> conflict-free (2-way, free).
  __shared__ u16 sA[BM * BK];   // 8 KB
  __shared__ u16 sB[BN * BK];   // 8 KB
  __shared__ float sPm[2][BM];
  __shared__ float sPs[2][BM];

  const int tid = threadIdx.x;
  const int wave = tid >> 6;
  const int lane = tid & 63;
  const int quad = lane >> 4;
  const int l16 = lane & 15;
  const int wr = wave >> 1, wc = wave & 1;  // 2x2 wave grid, each 64x64

  const int row0 = blockIdx.y * BM;
  const int col0 = blockIdx.x * CPB;

  // Staging: wave w stages k-chunk kc=w for all 128 rows of A and B.
  // Lane L covers row L (first 1KB wave-chunk) and row 64+L (second).
  const u16* aBase = Abf + (size_t)(row0 + lane) * DDIM + wave * 8;
  const u16* ldsA0 = &sA[wave * 1024];
  const u16* ldsA1 = &sA[wave * 1024 + 512];
  const u16* ldsB0 = &sB[wave * 1024];
  const u16* ldsB1 = &sB[wave * 1024 + 512];

  // Fragment read pointers: A row = wr*64 + mi*16 + l16, k = quad*8 + j
  const u16* pa = &sA[(quad * 128 + wr * 64 + l16) * 8];
  const u16* pb = &sB[(quad * 128 + wc * 64 + l16) * 8];

  // Per-lane running logsumexp state: lane owns row (wr*64+mi*16+quad*4+r)
  // for its 16 columns per tile (same rows every tile).
  float rm[4][4], rl[4][4];
#pragma unroll
  for (int mi = 0; mi < 4; ++mi)
#pragma unroll
    for (int r = 0; r < 4; ++r) { rm[mi][r] = -INFINITY; rl[mi][r] = 0.f; }

  for (int t = 0; t < TPB; ++t) {
    const u16* bBase = Bbf + (size_t)(col0 + t * BN + lane) * DDIM + wave * 8;

    f32x4 acc[4][4];
#pragma unroll
    for (int mi = 0; mi < 4; ++mi)
#pragma unroll
      for (int ni = 0; ni < 4; ++ni) acc[mi][ni] = (f32x4){0.f, 0.f, 0.f, 0.f};

    for (int kk = 0; kk < DDIM; kk += BK) {
      __syncthreads();  // protect LDS from previous step's readers
      gl2lds16(aBase + kk, ldsA0);
      gl2lds16(aBase + 64 * DDIM + kk, ldsA1);
      gl2lds16(bBase + kk, ldsB0);
      gl2lds16(bBase + 64 * DDIM + kk, ldsB1);
      __syncthreads();  // staging complete

      short8 af[4], bq[4];
#pragma unroll
      for (int i = 0; i < 4; ++i) {
        af[i] = *(const short8*)(pa + i * 128);
        bq[i] = *(const short8*)(pb + i * 128);
      }
#pragma unroll
      for (int mi = 0; mi < 4; ++mi)
#pragma unroll
        for (int ni = 0; ni < 4; ++ni)
          acc[mi][ni] =
              __builtin_amdgcn_mfma_f32_16x16x32_bf16(af[mi], bq[ni], acc[mi][ni], 0, 0, 0);
    }

    // Per-lane online LSE over this tile's 16 columns (no cross-lane work).
#pragma unroll
    for (int mi = 0; mi < 4; ++mi) {
#pragma unroll
      for (int r = 0; r < 4; ++r) {
        float v0 = acc[mi][0][r] * 10.0f;
        float v1 = acc[mi][1][r] * 10.0f;
        float v2 = acc[mi][2][r] * 10.0f;
        float v3 = acc[mi][3][r] * 10.0f;
        float vm = fmaxf(fmaxf(v0, v1), fmaxf(v2, v3));
        float nm = fmaxf(rm[mi][r], vm);
        rl[mi][r] = rl[mi][r] * __expf(rm[mi][r] - nm) +
                    (__expf(v0 - nm) + __expf(v1 - nm) + __expf(v2 - nm) + __expf(v3 - nm));
        rm[mi][r] = nm;
      }
    }
  }

  // Cross-lane merge over l16 (lanes sharing a row), once per block.
#pragma unroll
  for (int mi = 0; mi < 4; ++mi) {
#pragma unroll
    for (int r = 0; r < 4; ++r) {
      float m = rm[mi][r], l = rl[mi][r];
#pragma unroll
      for (int mask = 1; mask < 16; mask <<= 1) {
        float om = __shfl_xor(m, mask);
        float ol = __shfl_xor(l, mask);
        float nm = fmaxf(m, om);
        l = l * __expf(m - nm) + ol * __expf(om - nm);
        m = nm;
      }
      if (l16 == 0) {
        int rowl = wr * 64 + mi * 16 + quad * 4 + r;
        sPm[wc][rowl] = m;
        sPs[wc][rowl] = l;
      }
    }
  }
  __syncthreads();
  if (tid < BM) {
    float m0 = sPm[0][tid], m1 = sPm[1][tid];
    float s0 = sPs[0][tid], s1 = sPs[1][tid];
    float nm = fmaxf(m0, m1);
    size_t o = (size_t)blockIdx.x * NB + row0 + tid;
    partM[o] = nm;
    partL[o] = s0 * __expf(m0 - nm) + s1 * __expf(m1 - nm);
  }
}

__global__ void finalize_kernel(const float* __restrict__ partM,
                                const float* __restrict__ partL,
                                const float* __restrict__ diag, float* __restrict__ out) {
  __shared__ float red[256];
  float acc = 0.f;
  for (int r = threadIdx.x; r < NB; r += 256) {
    float M = -INFINITY;
#pragma unroll
    for (int s = 0; s < SPLITS; ++s) M = fmaxf(M, partM[(size_t)s * NB + r]);
    float L = 0.f;
#pragma unroll
    for (int s = 0; s < SPLITS; ++s)
      L += partL[(size_t)s * NB + r] * __expf(partM[(size_t)s * NB + r] - M);
    acc += M + __logf(L) - diag[r];
  }
  red[threadIdx.x] = acc;
  __syncthreads();
  for (int s = 128; s > 0; s >>= 1) {
    if (threadIdx.x < s) red[threadIdx.x] += red[threadIdx.x + s];
    __syncthreads();
  }
  if (threadIdx.x == 0) out[0] = red[0] * (1.0f / (float)NB);
}

extern "C" void kernel_launch(void* const* d_in, const int* in_sizes, int n_in,
                              void* d_out, int out_size, void* d_ws, size_t ws_size,
                              hipStream_t stream) {
  const float* anchor = (const float*)d_in[0];
  const float* positive = (const float*)d_in[1];
  float* out = (float*)d_out;

  char* ws = (char*)d_ws;
  u16* Abf = (u16*)ws;                                   // 8 MB
  u16* Bbf = (u16*)(ws + (size_t)8388608);               // 8 MB
  float* diag = (float*)(ws + (size_t)16777216);         // 32 KB
  float* partM = (float*)(ws + (size_t)16777216 + 32768);
  float* partL = (float*)(ws + (size_t)16777216 + 32768 + (size_t)SPLITS * NB * 4);

  cvt_diag_kernel<<<NB / 4, 256, 0, stream>>>(anchor, positive, Abf, Bbf, diag);
  gemm_lse<<<dim3(SPLITS, NB / BM), 256, 0, stream>>>(Abf, Bbf, partM, partL);
  finalize_kernel<<<1, 256, 0, stream>>>(partM, partL, diag, out);
}

// Round 3
// 259.454 us; speedup vs baseline: 1.2510x; 1.2510x over previous
//
#include <hip/hip_runtime.h>
#include <hip/hip_bf16.h>
#include <math.h>
#include <stdint.h>

// InfoNCE fused: sim = A @ B^T / T  (8192x8192x512, fp32 in)
// loss = mean_i( logsumexp_j sim[i,j] - sim[i,i] )
// bf16 MFMA GEMM + per-lane online logsumexp (epilogue once per block).

#define NB 8192
#define DDIM 512
#define SPLITS 16
#define BM 128
#define BN 128
#define BK 32
#define CPB (NB / SPLITS)   // 512 cols per block
#define TPB (CPB / BN)      // 4 col tiles per block

typedef unsigned short u16;
typedef __attribute__((ext_vector_type(8))) short short8;
typedef __attribute__((ext_vector_type(4))) float f32x4;

__device__ __forceinline__ u16 f2bf(float f) {
  unsigned u = __float_as_uint(f);
  u += 0x7FFFu + ((u >> 16) & 1u);   // round-to-nearest-even
  return (u16)(u >> 16);
}

// global -> LDS direct copy, 16B per lane: HW writes ldsbase + lane*16.
__device__ __forceinline__ void gl2lds16(const u16* g, const u16* l) {
  __builtin_amdgcn_global_load_lds(
      (__attribute__((address_space(1))) unsigned int*)(uintptr_t)g,
      (__attribute__((address_space(3))) unsigned int*)(unsigned int)(uintptr_t)l,
      16, 0, 0);
}

// One wave per row: convert a & p rows to bf16 and compute diag dot in fp32.
__global__ void cvt_diag_kernel(const float* __restrict__ a, const float* __restrict__ p,
                                u16* __restrict__ ab, u16* __restrict__ pb,
                                float* __restrict__ diag) {
  int row = (blockIdx.x * 256 + threadIdx.x) >> 6;
  int lane = threadIdx.x & 63;
  const float4* ar = (const float4*)(a + (size_t)row * DDIM + lane * 8);
  const float4* pr = (const float4*)(p + (size_t)row * DDIM + lane * 8);
  float4 a0 = ar[0], a1 = ar[1];
  float4 p0 = pr[0], p1 = pr[1];
  ushort4* abr = (ushort4*)(ab + (size_t)row * DDIM + lane * 8);
  ushort4* pbr = (ushort4*)(pb + (size_t)row * DDIM + lane * 8);
  abr[0] = (ushort4){f2bf(a0.x), f2bf(a0.y), f2bf(a0.z), f2bf(a0.w)};
  abr[1] = (ushort4){f2bf(a1.x), f2bf(a1.y), f2bf(a1.z), f2bf(a1.w)};
  pbr[0] = (ushort4){f2bf(p0.x), f2bf(p0.y), f2bf(p0.z), f2bf(p0.w)};
  pbr[1] = (ushort4){f2bf(p1.x), f2bf(p1.y), f2bf(p1.z), f2bf(p1.w)};
  float s = a0.x * p0.x + a0.y * p0.y + a0.z * p0.z + a0.w * p0.w +
            a1.x * p1.x + a1.y * p1.y + a1.z * p1.z + a1.w * p1.w;
  for (int off = 32; off > 0; off >>= 1) s += __shfl_down(s, off);
  if (lane == 0) diag[row] = s * 10.0f;  // / T
}

__global__ __launch_bounds__(256, 3) void gemm_lse(
    const u16* __restrict__ Abf, const u16* __restrict__ Bbf,
    float* __restrict__ partM, float* __restrict__ partL) {
  // m97-style LDS layout: sA[row*BK + k], row stride 64B. Bank conflicts on
  // fragment reads exist (8-way) but are empirically not the limiter (m97/m98).
  __shared__ u16 sA[BM * BK];   // 8 KB
  __shared__ u16 sB[BN * BK];   // 8 KB
  __shared__ float sPm[2][BM];
  __shared__ float sPs[2][BM];

  const int tid = threadIdx.x;
  const int wave = tid >> 6;
  const int lane = tid & 63;
  const int quad = lane >> 4;
  const int l16 = lane & 15;
  const int wr = wave >> 1, wc = wave & 1;  // 2x2 wave grid, each 64x64

  const int row0 = blockIdx.y * BM;
  const int col0 = blockIdx.x * CPB;

  // Staging: wave covers rows wave*16 + rsub (and +64), 64B runs per row.
  const int rsub = lane >> 2;         // 0..15 row within chunk
  const int ksub = (lane & 3) * 8;    // k elem offset
  const u16* aBase = Abf + (size_t)(row0 + wave * 16 + rsub) * DDIM + ksub;
  const u16* ldsA0 = &sA[wave * 512];
  const u16* ldsA1 = &sA[2048 + wave * 512];
  const u16* ldsB0 = &sB[wave * 512];
  const u16* ldsB1 = &sB[2048 + wave * 512];

  // Fragment read pointers: A row = wr*64 + mi*16 + l16, k = quad*8 + j
  const u16* pa = &sA[(wr * 64 + l16) * BK + quad * 8];
  const u16* pb = &sB[(wc * 64 + l16) * BK + quad * 8];

  // Per-lane running LSE: lane owns row wr*64 + mi*16 + quad*4 + r,
  // columns (col0.. ; l16-sliced). Same rows every tile.
  float rm[4][4], rl[4][4];
#pragma unroll
  for (int mi = 0; mi < 4; ++mi)
#pragma unroll
    for (int r = 0; r < 4; ++r) { rm[mi][r] = -INFINITY; rl[mi][r] = 0.f; }

  for (int t = 0; t < TPB; ++t) {
    const u16* bBase = Bbf + (size_t)(col0 + t * BN + wave * 16 + rsub) * DDIM + ksub;

    f32x4 acc[4][4];
#pragma unroll
    for (int mi = 0; mi < 4; ++mi)
#pragma unroll
      for (int ni = 0; ni < 4; ++ni) acc[mi][ni] = (f32x4){0.f, 0.f, 0.f, 0.f};

    for (int kk = 0; kk < DDIM; kk += BK) {
      __syncthreads();  // protect LDS from previous round's readers
      gl2lds16(aBase + kk, ldsA0);
      gl2lds16(aBase + 64 * DDIM + kk, ldsA1);
      gl2lds16(bBase + kk, ldsB0);
      gl2lds16(bBase + 64 * DDIM + kk, ldsB1);
      __syncthreads();  // staging complete

      short8 af[4], bq[4];
#pragma unroll
      for (int i = 0; i < 4; ++i) {
        af[i] = *(const short8*)(pa + i * 16 * BK);
        bq[i] = *(const short8*)(pb + i * 16 * BK);
      }
#pragma unroll
      for (int mi = 0; mi < 4; ++mi)
#pragma unroll
        for (int ni = 0; ni < 4; ++ni)
          acc[mi][ni] =
              __builtin_amdgcn_mfma_f32_16x16x32_bf16(af[mi], bq[ni], acc[mi][ni], 0, 0, 0);
    }

    // Per-lane online LSE over this tile's 16 columns (no cross-lane work).
#pragma unroll
    for (int mi = 0; mi < 4; ++mi) {
#pragma unroll
      for (int r = 0; r < 4; ++r) {
        float v0 = acc[mi][0][r] * 10.0f;
        float v1 = acc[mi][1][r] * 10.0f;
        float v2 = acc[mi][2][r] * 10.0f;
        float v3 = acc[mi][3][r] * 10.0f;
        float vm = fmaxf(fmaxf(v0, v1), fmaxf(v2, v3));
        float nm = fmaxf(rm[mi][r], vm);
        rl[mi][r] = rl[mi][r] * __expf(rm[mi][r] - nm) +
                    (__expf(v0 - nm) + __expf(v1 - nm) + __expf(v2 - nm) + __expf(v3 - nm));
        rm[mi][r] = nm;
      }
    }
  }

  // Cross-lane merge over l16 (lanes sharing a row), once per block.
#pragma unroll
  for (int mi = 0; mi < 4; ++mi) {
#pragma unroll
    for (int r = 0; r < 4; ++r) {
      float m = rm[mi][r], l = rl[mi][r];
#pragma unroll
      for (int mask = 1; mask < 16; mask <<= 1) {
        float om = __shfl_xor(m, mask);
        float ol = __shfl_xor(l, mask);
        float nm = fmaxf(m, om);
        l = l * __expf(m - nm) + ol * __expf(om - nm);
        m = nm;
      }
      if (l16 == 0) {
        int rowl = wr * 64 + mi * 16 + quad * 4 + r;
        sPm[wc][rowl] = m;
        sPs[wc][rowl] = l;
      }
    }
  }
  __syncthreads();
  if (tid < BM) {
    float m0 = sPm[0][tid], m1 = sPm[1][tid];
    float s0 = sPs[0][tid], s1 = sPs[1][tid];
    float nm = fmaxf(m0, m1);
    size_t o = (size_t)blockIdx.x * NB + row0 + tid;
    partM[o] = nm;
    partL[o] = s0 * __expf(m0 - nm) + s1 * __expf(m1 - nm);
  }
}

__global__ void zero_kernel(float* __restrict__ out) { out[0] = 0.f; }

// One row per thread, 32 blocks; block-sum -> atomicAdd.
__global__ void reduce_kernel(const float* __restrict__ partM,
                              const float* __restrict__ partL,
                              const float* __restrict__ diag, float* __restrict__ out) {
  __shared__ float red[4];
  int r = blockIdx.x * 256 + threadIdx.x;
  float M = -INFINITY;
#pragma unroll
  for (int s = 0; s < SPLITS; ++s) M = fmaxf(M, partM[(size_t)s * NB + r]);
  float L = 0.f;
#pragma unroll
  for (int s = 0; s < SPLITS; ++s)
    L += partL[(size_t)s * NB + r] * __expf(partM[(size_t)s * NB + r] - M);
  float v = M + __logf(L) - diag[r];
  for (int off = 32; off > 0; off >>= 1) v += __shfl_down(v, off);
  if ((threadIdx.x & 63) == 0) red[threadIdx.x >> 6] = v;
  __syncthreads();
  if (threadIdx.x == 0) {
    float s = (red[0] + red[1] + red[2] + red[3]) * (1.0f / (float)NB);
    atomicAdd(out, s);
  }
}

extern "C" void kernel_launch(void* const* d_in, const int* in_sizes, int n_in,
                              void* d_out, int out_size, void* d_ws, size_t ws_size,
                              hipStream_t stream) {
  const float* anchor = (const float*)d_in[0];
  const float* positive = (const float*)d_in[1];
  float* out = (float*)d_out;

  char* ws = (char*)d_ws;
  u16* Abf = (u16*)ws;                                   // 8 MB
  u16* Bbf = (u16*)(ws + (size_t)8388608);               // 8 MB
  float* diag = (float*)(ws + (size_t)16777216);         // 32 KB
  float* partM = (float*)(ws + (size_t)16777216 + 32768);
  float* partL = (float*)(ws + (size_t)16777216 + 32768 + (size_t)SPLITS * NB * 4);

  cvt_diag_kernel<<<NB / 4, 256, 0, stream>>>(anchor, positive, Abf, Bbf, diag);
  gemm_lse<<<dim3(SPLITS, NB / BM), 256, 0, stream>>>(Abf, Bbf, partM, partL);
  zero_kernel<<<1, 64, 0, stream>>>(out);
  reduce_kernel<<<NB / 256, 256, 0, stream>>>(partM, partL, diag, out);
}

// Round 4
// 237.753 us; speedup vs baseline: 1.3652x; 1.0913x over previous
//
#include <hip/hip_runtime.h>
#include <hip/hip_bf16.h>
#include <math.h>
#include <stdint.h>

// InfoNCE fused: sim = A @ B^T / T  (8192x8192x512, fp32 in)
// loss = mean_i( logsumexp_j sim[i,j] - sim[i,i] )
// bf16 MFMA GEMM; per-tile cross-lane LSE -> global partials (stateless
// epilogue: rounds 2/3 showed any per-lane running LSE state spills acc).

#define NB 8192
#define DDIM 512
#define SPLITS 16
#define BM 128
#define BN 128
#define BK 32
#define CPB (NB / SPLITS)        // 512 cols per block
#define TPB (CPB / BN)           // 4 col tiles per block
#define NPART (SPLITS * TPB * 2) // 128 (m,l) partials per row

typedef unsigned short u16;
typedef __attribute__((ext_vector_type(8))) short short8;
typedef __attribute__((ext_vector_type(4))) float f32x4;

__device__ __forceinline__ u16 f2bf(float f) {
  unsigned u = __float_as_uint(f);
  u += 0x7FFFu + ((u >> 16) & 1u);   // round-to-nearest-even
  return (u16)(u >> 16);
}

// global -> LDS direct copy, 16B per lane: HW writes ldsbase + lane*16.
__device__ __forceinline__ void gl2lds16(const u16* g, const u16* l) {
  __builtin_amdgcn_global_load_lds(
      (__attribute__((address_space(1))) unsigned int*)(uintptr_t)g,
      (__attribute__((address_space(3))) unsigned int*)(unsigned int)(uintptr_t)l,
      16, 0, 0);
}

// One wave per row: convert a & p rows to bf16 and compute diag dot in fp32.
__global__ void cvt_diag_kernel(const float* __restrict__ a, const float* __restrict__ p,
                                u16* __restrict__ ab, u16* __restrict__ pb,
                                float* __restrict__ diag) {
  int row = (blockIdx.x * 256 + threadIdx.x) >> 6;
  int lane = threadIdx.x & 63;
  const float4* ar = (const float4*)(a + (size_t)row * DDIM + lane * 8);
  const float4* pr = (const float4*)(p + (size_t)row * DDIM + lane * 8);
  float4 a0 = ar[0], a1 = ar[1];
  float4 p0 = pr[0], p1 = pr[1];
  ushort4* abr = (ushort4*)(ab + (size_t)row * DDIM + lane * 8);
  ushort4* pbr = (ushort4*)(pb + (size_t)row * DDIM + lane * 8);
  abr[0] = (ushort4){f2bf(a0.x), f2bf(a0.y), f2bf(a0.z), f2bf(a0.w)};
  abr[1] = (ushort4){f2bf(a1.x), f2bf(a1.y), f2bf(a1.z), f2bf(a1.w)};
  pbr[0] = (ushort4){f2bf(p0.x), f2bf(p0.y), f2bf(p0.z), f2bf(p0.w)};
  pbr[1] = (ushort4){f2bf(p1.x), f2bf(p1.y), f2bf(p1.z), f2bf(p1.w)};
  float s = a0.x * p0.x + a0.y * p0.y + a0.z * p0.z + a0.w * p0.w +
            a1.x * p1.x + a1.y * p1.y + a1.z * p1.z + a1.w * p1.w;
  for (int off = 32; off > 0; off >>= 1) s += __shfl_down(s, off);
  if (lane == 0) diag[row] = s * 10.0f;  // / T
}

__global__ __launch_bounds__(256, 4) void gemm_lse(
    const u16* __restrict__ Abf, const u16* __restrict__ Bbf,
    float* __restrict__ partM, float* __restrict__ partL) {
  // m97-style LDS layout: sA[row*BK + k]. 8-way bank conflicts on fragment
  // reads tolerated (empirically not the limiter: m97/m98, round 1 vs 2).
  __shared__ u16 sA[BM * BK];   // 8 KB
  __shared__ u16 sB[BN * BK];   // 8 KB

  const int tid = threadIdx.x;
  const int wave = tid >> 6;
  const int lane = tid & 63;
  const int quad = lane >> 4;
  const int l16 = lane & 15;
  const int wr = wave >> 1, wc = wave & 1;  // 2x2 wave grid, each 64x64

  const int row0 = blockIdx.x * BM;        // x = row tile (L2: consecutive
  const int col0 = blockIdx.y * CPB;       // blocks share the B strip)

  // Staging: wave covers rows wave*16 + rsub (and +64), 64B runs per row.
  const int rsub = lane >> 2;         // 0..15 row within chunk
  const int ksub = (lane & 3) * 8;    // k elem offset
  const u16* aBase = Abf + (size_t)(row0 + wave * 16 + rsub) * DDIM + ksub;
  const u16* ldsA0 = &sA[wave * 512];
  const u16* ldsA1 = &sA[2048 + wave * 512];
  const u16* ldsB0 = &sB[wave * 512];
  const u16* ldsB1 = &sB[2048 + wave * 512];

  // Fragment read pointers: A row = wr*64 + mi*16 + l16, k = quad*8 + j
  const u16* pa = &sA[(wr * 64 + l16) * BK + quad * 8];
  const u16* pb = &sB[(wc * 64 + l16) * BK + quad * 8];

  for (int t = 0; t < TPB; ++t) {
    const u16* bBase = Bbf + (size_t)(col0 + t * BN + wave * 16 + rsub) * DDIM + ksub;

    f32x4 acc[4][4];
#pragma unroll
    for (int mi = 0; mi < 4; ++mi)
#pragma unroll
      for (int ni = 0; ni < 4; ++ni) acc[mi][ni] = (f32x4){0.f, 0.f, 0.f, 0.f};

    for (int kk = 0; kk < DDIM; kk += BK) {
      __syncthreads();  // protect LDS from previous step's readers
      gl2lds16(aBase + kk, ldsA0);
      gl2lds16(aBase + 64 * DDIM + kk, ldsA1);
      gl2lds16(bBase + kk, ldsB0);
      gl2lds16(bBase + 64 * DDIM + kk, ldsB1);
      __syncthreads();  // staging complete

      short8 af[4], bq[4];
#pragma unroll
      for (int i = 0; i < 4; ++i) {
        af[i] = *(const short8*)(pa + i * 16 * BK);
        bq[i] = *(const short8*)(pb + i * 16 * BK);
      }
#pragma unroll
      for (int mi = 0; mi < 4; ++mi)
#pragma unroll
        for (int ni = 0; ni < 4; ++ni)
          acc[mi][ni] =
              __builtin_amdgcn_mfma_f32_16x16x32_bf16(af[mi], bq[ni], acc[mi][ni], 0, 0, 0);
    }

    // Stateless per-tile LSE: shfl-merge over the 16 l16 lanes (64 cols),
    // then lane l16==0 writes this tile's (m,l) partial to global.
    const int p = (blockIdx.y * TPB + t) * 2 + wc;
#pragma unroll
    for (int mi = 0; mi < 4; ++mi) {
#pragma unroll
      for (int r = 0; r < 4; ++r) {
        float v0 = acc[mi][0][r] * 10.0f;  // apply 1/T
        float v1 = acc[mi][1][r] * 10.0f;
        float v2 = acc[mi][2][r] * 10.0f;
        float v3 = acc[mi][3][r] * 10.0f;
        float mx = fmaxf(fmaxf(v0, v1), fmaxf(v2, v3));
        mx = fmaxf(mx, __shfl_xor(mx, 1));
        mx = fmaxf(mx, __shfl_xor(mx, 2));
        mx = fmaxf(mx, __shfl_xor(mx, 4));
        mx = fmaxf(mx, __shfl_xor(mx, 8));
        float s = __expf(v0 - mx) + __expf(v1 - mx) + __expf(v2 - mx) + __expf(v3 - mx);
        s += __shfl_xor(s, 1);
        s += __shfl_xor(s, 2);
        s += __shfl_xor(s, 4);
        s += __shfl_xor(s, 8);
        if (l16 == 0) {
          int row = row0 + wr * 64 + mi * 16 + quad * 4 + r;
          partM[(size_t)p * NB + row] = mx;
          partL[(size_t)p * NB + row] = s;
        }
      }
    }
  }
}

__global__ void zero_kernel(float* __restrict__ out) { out[0] = 0.f; }

// One row per thread, 32 blocks; block-sum -> atomicAdd.
__global__ void reduce_kernel(const float* __restrict__ partM,
                              const float* __restrict__ partL,
                              const float* __restrict__ diag, float* __restrict__ out) {
  __shared__ float red[4];
  int r = blockIdx.x * 256 + threadIdx.x;
  float M = -INFINITY;
  for (int s = 0; s < NPART; ++s) M = fmaxf(M, partM[(size_t)s * NB + r]);
  float L = 0.f;
  for (int s = 0; s < NPART; ++s)
    L += partL[(size_t)s * NB + r] * __expf(partM[(size_t)s * NB + r] - M);
  float v = M + __logf(L) - diag[r];
  for (int off = 32; off > 0; off >>= 1) v += __shfl_down(v, off);
  if ((threadIdx.x & 63) == 0) red[threadIdx.x >> 6] = v;
  __syncthreads();
  if (threadIdx.x == 0) {
    float s = (red[0] + red[1] + red[2] + red[3]) * (1.0f / (float)NB);
    atomicAdd(out, s);
  }
}

extern "C" void kernel_launch(void* const* d_in, const int* in_sizes, int n_in,
                              void* d_out, int out_size, void* d_ws, size_t ws_size,
                              hipStream_t stream) {
  const float* anchor = (const float*)d_in[0];
  const float* positive = (const float*)d_in[1];
  float* out = (float*)d_out;

  char* ws = (char*)d_ws;
  u16* Abf = (u16*)ws;                                   // 8 MB
  u16* Bbf = (u16*)(ws + (size_t)8388608);               // 8 MB
  float* diag = (float*)(ws + (size_t)16777216);         // 32 KB
  float* partM = (float*)(ws + (size_t)16777216 + 32768);            // 4 MB
  float* partL = (float*)(ws + (size_t)16777216 + 32768 + (size_t)NPART * NB * 4);

  cvt_diag_kernel<<<NB / 4, 256, 0, stream>>>(anchor, positive, Abf, Bbf, diag);
  gemm_lse<<<dim3(NB / BM, SPLITS), 256, 0, stream>>>(Abf, Bbf, partM, partL);
  zero_kernel<<<1, 64, 0, stream>>>(out);
  reduce_kernel<<<NB / 256, 256, 0, stream>>>(partM, partL, diag, out);
}